// Round 1
// 1306.278 us; speedup vs baseline: 1.0462x; 1.0462x over previous
//
#include <hip/hip_runtime.h>

// SegmentCSR sum: out[s, :] = sum_{r in [indptr[s], indptr[s+1])} x[r, :]
// x: [TOTAL, 128] fp32 (rows of a segment are CONTIGUOUS in memory)
// indptr: [N_SEG+1] int32 (JAX x64 disabled -> int64 request lowers to int32)
// out: [N_SEG, 128] fp32
//
// One wave per segment; lane L covers float4-column (L&31), row-phase (L>>5),
// so each wave iteration reads 2 rows = 1 KiB fully coalesced.
// V2 changes vs baseline (theory: concurrency-limited at ~1.7 TB/s):
//  - unroll x4 with independent accumulators -> 4 loads (4 KiB) in flight
//    per wave instead of 1 (load->waitcnt(0)->add serialization)
//  - 128-thread blocks (2 waves): workgroup retires on max-of-2 exp-distributed
//    segment lengths (1.5x mean) instead of max-of-4 (2.08x mean)
//  - nontemporal loads/stores: x is read-once, out is write-once; keep L2
//    for the hot 256 KB indptr

#define NSEG 65536
#define D4   32   // 128 floats = 32 float4

typedef float f32x4 __attribute__((ext_vector_type(4)));

__global__ __launch_bounds__(128) void segcsr_kernel(
    const f32x4* __restrict__ x,      // [TOTAL * 32] float4
    const int*   __restrict__ indptr, // [NSEG + 1]
    f32x4*       __restrict__ out)    // [NSEG * 32] float4
{
    const int seg  = (blockIdx.x << 1) + (threadIdx.x >> 6); // 2 waves/block
    const int lane = threadIdx.x & 63;
    const int c    = lane & 31;   // float4 column
    const int rh   = lane >> 5;   // row phase: 0 or 1

    const int begin = indptr[seg];
    const int end   = indptr[seg + 1];
    const int len   = end - begin;

    // iterations for this row-phase stream: rows begin+rh, begin+rh+2, ... < end
    int k = (len + 1 - rh) >> 1;  // len >= 0 -> non-negative

    const f32x4* p = x + (size_t)(begin + rh) * D4 + c;

    f32x4 a0 = {0.f, 0.f, 0.f, 0.f};
    f32x4 a1 = {0.f, 0.f, 0.f, 0.f};
    f32x4 a2 = {0.f, 0.f, 0.f, 0.f};
    f32x4 a3 = {0.f, 0.f, 0.f, 0.f};

    // Macro-iteration: 4 independent 1 KiB wave-loads in flight (8 rows).
    while (k >= 4) {
        f32x4 v0 = __builtin_nontemporal_load(p);
        f32x4 v1 = __builtin_nontemporal_load(p + 64);
        f32x4 v2 = __builtin_nontemporal_load(p + 128);
        f32x4 v3 = __builtin_nontemporal_load(p + 192);
        a0 += v0; a1 += v1; a2 += v2; a3 += v3;
        p += 256;   // 8 rows * 32 float4
        k -= 4;
    }
    while (k > 0) {
        a0 += __builtin_nontemporal_load(p);
        p += 64;    // 2 rows
        k -= 1;
    }

    f32x4 a = (a0 + a1) + (a2 + a3);

    // Fold the two half-wave partials (same column, rows offset by 1).
    a.x += __shfl_down(a.x, 32);
    a.y += __shfl_down(a.y, 32);
    a.z += __shfl_down(a.z, 32);
    a.w += __shfl_down(a.w, 32);

    if (rh == 0) {
        __builtin_nontemporal_store(a, out + (size_t)seg * D4 + c);
    }
}

extern "C" void kernel_launch(void* const* d_in, const int* in_sizes, int n_in,
                              void* d_out, int out_size, void* d_ws, size_t ws_size,
                              hipStream_t stream) {
    const f32x4* x      = (const f32x4*)d_in[0];
    const int*   indptr = (const int*)d_in[1];
    f32x4*       out    = (f32x4*)d_out;

    // 2 segments (waves) per 128-thread block.
    dim3 grid(NSEG / 2), block(128);
    segcsr_kernel<<<grid, block, 0, stream>>>(x, indptr, out);
}